// Round 16
// baseline (211.252 us; speedup 1.0000x reference)
//
#include <hip/hip_runtime.h>
#include <hip/hip_bf16.h>
#include <math.h>

// Fused GNN readout via bf16 MFMA (v_mfma_f32_32x32x16_bf16):
//   feat1 = relu(concat(h,x) @ W1 + b1)   [N,256]  GEMM1: K=400(pad 448), A=bf16 hi, B=W1 hi ONLY
//   feat2 = relu(feat1 @ W2 + b2)         [N,64]   GEMM2: K=256 (2-way K-split), A=bf16 hi, B=W2 hi+lo
//   s_n   = feat2 . Wout ; out = sigmoid(segment_sum(s_n) + bout)
// R16 = R14/R15 pipeline + occupancy fix via work decomposition:
//   R15 proved the 64-AGPR/wave accumulator pins unified regs at ~148 -> 2
//   waves/SIMD regardless of launch_bounds. Fix: 512-thread / 8-wave blocks,
//   same 64x256 tile; wave owns (row-half, col-quarter) -> acc = 32 AGPR,
//   1 A-frag/step -> unified ~95 -> 4 waves/SIMD = ~50% occupancy.
//   GEMM2: 2-way K-split across wave halves + LDS partial combine (ring buf 2).
//   Counted-vmcnt (margin >=4, never 0), no sched_barrier, no setprio.

typedef __attribute__((ext_vector_type(8)))  short short8v;
typedef __attribute__((ext_vector_type(16))) float f32x16;

#define G_NUM 2048
#define HID 200
#define EMB 200
#define DIN 400
#define NH1 256
#define NH2 64
#define BM  64
#define NKS1 28        // bf16 K-steps (of 16) for GEMM1, K padded 400->448
#define NCH  7         // 7 chunks of 64 fp32 cols
#define NKS2 16        // K-steps for GEMM2 (K=256)

#define W1P_SH8 (NKS1*8*64)   // 14336 fragments (16B each), hi plane only
#define W2P_SH8 (NKS2*2*64)   // 2048

__device__ __forceinline__ unsigned short f2bf(float f) {
    union { float f; unsigned u; } v; v.f = f;
    unsigned r = v.u + 0x7fffu + ((v.u >> 16) & 1u);   // RNE
    return (unsigned short)(r >> 16);
}
__device__ __forceinline__ float bf2f(unsigned short b) {
    union { unsigned u; float f; } v; v.u = ((unsigned)b) << 16;
    return v.f;
}
// 8 fp32 -> 8 bf16 (RNE) via packed converts
__device__ __forceinline__ short8v cvt8(float4 a, float4 b) {
    union { __hip_bfloat162 q[4]; short8v s8; } u;
    u.q[0] = __float22bfloat162_rn(make_float2(a.x, a.y));
    u.q[1] = __float22bfloat162_rn(make_float2(a.z, a.w));
    u.q[2] = __float22bfloat162_rn(make_float2(b.x, b.y));
    u.q[3] = __float22bfloat162_rn(make_float2(b.z, b.w));
    return u.s8;
}

// Pre-pack W1 (hi only) / W2 (hi+lo) into MFMA-fragment order.
// Fragment (ks, ntile, lane) holds 8 bf16: B[k0+j][col], k0=ks*16+(lane>>5)*8,
// col=ntile*32+(lane&31). Contiguous-8 k in BOTH A and B => any consistent
// hw k-permutation cancels in the dot product.
__global__ void pack_weights(const float* __restrict__ W1, const float* __restrict__ W2,
                             unsigned short* __restrict__ w1h,
                             unsigned short* __restrict__ w2h, unsigned short* __restrict__ w2l)
{
    int idx = blockIdx.x * 256 + threadIdx.x;
    if (idx < W1P_SH8) {
        int l  = idx & 63;
        int nt = (idx >> 6) & 7;
        int ks = idx >> 9;
        int col = nt * 32 + (l & 31);
        int k0  = ks * 16 + (l >> 5) * 8;
        short8v H;
        #pragma unroll
        for (int j = 0; j < 8; ++j) {
            int k = k0 + j;
            H[j] = (short)f2bf((k < DIN) ? W1[(size_t)k * NH1 + col] : 0.f);
        }
        ((short8v*)w1h)[idx] = H;
    } else if (idx < W1P_SH8 + W2P_SH8) {
        int i2 = idx - W1P_SH8;
        int l  = i2 & 63;
        int nt = (i2 >> 6) & 1;
        int ks = i2 >> 7;
        int col = nt * 32 + (l & 31);
        int k0  = ks * 16 + (l >> 5) * 8;
        short8v H, L;
        #pragma unroll
        for (int j = 0; j < 8; ++j) {
            float v = W2[(size_t)(k0 + j) * NH2 + col];
            unsigned short hh = f2bf(v);
            H[j] = (short)hh;
            L[j] = (short)f2bf(v - bf2f(hh));
        }
        ((short8v*)w2h)[i2] = H;
        ((short8v*)w2l)[i2] = L;
    }
}

__launch_bounds__(512, 4)
__global__ void fused_readout(const float* __restrict__ h, const float* __restrict__ x,
                              const int* __restrict__ batch,
                              const unsigned short* __restrict__ w1h,
                              const unsigned short* __restrict__ w2h, const unsigned short* __restrict__ w2l,
                              const float* __restrict__ b1, const float* __restrict__ b2,
                              const float* __restrict__ Wout, const float* __restrict__ zbuf,
                              float* __restrict__ gf1d, int N)
{
    // 49152 B LDS, time-multiplexed:
    //   [GEMM1] A fp32 ring: 3 bufs x [64 rows][64 fp32] = 49152 B
    //           (row stride 256 B; 16B-granule XOR swizzle c16 ^= row&15 applied
    //            on the GLOBAL SOURCE; LDS dest linear for global_load_lds)
    //   [GEMM2] F1h [64][256] bf16 = 32768 B (overlays ring bufs 0-1);
    //           K-split partials: 4 x 32x32 fp32 = 16384 B (overlays ring buf 2)
    //   [pool ] s2p[2][64] f32 at 0, srow[64] f32 at byte 512 (after F1h dead)
    __shared__ __align__(16) char lds[49152];
    unsigned short* F1h = (unsigned short*)lds;
    float* Part = (float*)(lds + 32768);   // 4096 floats
    float* s2p  = (float*)lds;             // 128 floats
    float* srow = (float*)(lds + 512);     // 64 floats

    const int t    = threadIdx.x;
    const int lane = t & 63;
    const int w    = t >> 6;            // 0..7
    const int n0   = blockIdx.x * BM;
    const int l31  = lane & 31;
    const int hs   = lane >> 5;         // k-half select

    const int wr = w & 1;               // GEMM1 row-half (32 rows)
    const int wc = w >> 1;              // GEMM1 col-quarter (64 cols = 2 ntiles)

    const short8v* W1H = (const short8v*)w1h;

    f32x16 acc0, acc1;                  // 2 x 32x32 tiles = 32 AGPR
    #pragma unroll
    for (int r = 0; r < 16; ++r) { acc0[r] = 0.f; acc1[r] = 0.f; }

    // ---- helpers ----
    // issue 2 global_load_lds covering this wave's 8 rows of chunk CH into ring buffer BUF
    // dest: linear  BUF*16384 + brow*256 + lane*16
    // src : per-lane, pre-swizzled col16 = (lane&15) ^ (row&15); OOB -> zbuf
    #define AISSUE(CH, BUF) do {                                               \
        _Pragma("unroll")                                                      \
        for (int ii = 0; ii < 2; ++ii) {                                       \
            int brow = w*8 + ii*4;                                             \
            int row  = brow + (lane >> 4);                                     \
            int node = n0 + row;                                               \
            int colf = (CH)*64 + (((lane & 15) ^ (row & 15)) << 2);            \
            const float* src;                                                  \
            if (node >= N || colf >= DIN) src = zbuf + (lane & 15)*4;          \
            else if (colf < HID)          src = h + (size_t)node*HID + colf;   \
            else                          src = x + (size_t)node*EMB + (colf - HID); \
            __builtin_amdgcn_global_load_lds(                                  \
                (const __attribute__((address_space(1))) unsigned*)src,        \
                (__attribute__((address_space(3))) unsigned*)(lds + (BUF)*16384 + brow*256 + lane*16), \
                16, 0, 0);                                                     \
        } } while (0)

    // A fragment: row ROW, logical col16 pair {S*4+hs*2, +1} of ring buffer (byte base HB)
    #define AFRAG(HB, S, ROW)                                                  \
        cvt8(*(const float4*)(lds + (HB) + (ROW)*256 + ((((S)*4 + hs*2)     ^ ((ROW) & 15)) << 4)), \
             *(const float4*)(lds + (HB) + (ROW)*256 + ((((S)*4 + hs*2 + 1) ^ ((ROW) & 15)) << 4)))

    // load one k-step's 2 B hi-fragments (this wave's col-quarter)
    #define BLOAD2(KS, H0, H1) do {                                            \
        size_t nb_ = ((size_t)((KS)*8 + wc*2))*64 + lane;                      \
        H0 = W1H[nb_]; H1 = W1H[nb_ + 64]; } while (0)

    // ---- prologue: A chunks 0,1 in flight; B ksteps 0,1 in regs-in-flight ----
    AISSUE(0, 0);
    AISSUE(1, 1);
    short8v c0h0, c0h1;    // B(ks)   — consumed this k-step
    short8v c1h0, c1h1;    // B(ks+1)
    BLOAD2(0, c0h0, c0h1);
    BLOAD2(1, c1h0, c1h1);

    // ================= GEMM1: 7 chunks x 4 k-steps, counted-vmcnt pipeline =================
    #pragma unroll
    for (int c = 0; c < NCH; ++c) {
        // Per-wave loads newer than A(c)'s 2 loads (issue order: A0:2,A1:2,Bp:4,
        // then per chunk: A(c+2):2 + B:8):
        //   c=0: 6   c=1: 14   c>=2: 18 (16 at c=6).
        // Counted waits with margin >=4 — never 0, never exact.
        if      (c == 0) { asm volatile("s_waitcnt vmcnt(2)"  ::: "memory"); }
        else if (c == 1) { asm volatile("s_waitcnt vmcnt(10)" ::: "memory"); }
        else             { asm volatile("s_waitcnt vmcnt(12)" ::: "memory"); }
        __builtin_amdgcn_s_barrier();   // all waves' A(c) complete; ring (c+2)%3 free
        if (c + 2 < NCH) AISSUE(c + 2, (c + 2) % 3);

        const int hb = (c % 3) * 16384;
        #pragma unroll
        for (int s = 0; s < 4; ++s) {
            const int ks = c * 4 + s;
            // prefetch B(ks+2) (depth 2; dummy ks=0 at tail)
            short8v n2h0, n2h1;
            BLOAD2((ks + 2 < NKS1) ? ks + 2 : 0, n2h0, n2h1);
            // A fragment (LDS ring) + convert
            short8v ah = AFRAG(hb, s, wr*32 + l31);
            acc0 = __builtin_amdgcn_mfma_f32_32x32x16_bf16(ah, c0h0, acc0, 0,0,0);
            acc1 = __builtin_amdgcn_mfma_f32_32x32x16_bf16(ah, c0h1, acc1, 0,0,0);
            // rotate B pipeline
            c0h0 = c1h0; c0h1 = c1h1;
            c1h0 = n2h0; c1h1 = n2h1;
        }
    }
    #undef BLOAD2
    #undef AFRAG
    #undef AISSUE

    __syncthreads();   // all ring reads done; F1h may overwrite bufs 0-1

    // ---- epilogue1: bias + relu + bf16 (hi only) -> F1h (XOR-swizzled) ----
    // C/D layout: col = lane&31, row = (r&3) + 8*(r>>2) + 4*(lane>>5)
    {
        const float b1c0 = b1[wc*64 + l31];
        const float b1c1 = b1[wc*64 + 32 + l31];
#define EPI1(ACC, NI) do {                                                \
        int gcol = wc*64 + (NI)*32 + l31;                                 \
        float bb = (NI) ? b1c1 : b1c0;                                    \
        _Pragma("unroll")                                                 \
        for (int r = 0; r < 16; ++r) {                                    \
            int grow = wr*32 + (r & 3) + 8*(r >> 2) + 4*hs;               \
            float v = fmaxf(ACC[r] + bb, 0.f);                            \
            int phys = grow*256 + (((gcol >> 3) ^ (grow & 31)) << 3) + (gcol & 7); \
            F1h[phys] = f2bf(v);                                          \
        } } while (0)
        EPI1(acc0, 0); EPI1(acc1, 1);
#undef EPI1
    }
    __syncthreads();

    // ================= GEMM2: feat2 = relu(feat1 @ W2 + b2), 2-way K-split =================
    // Wave w: row-half m2 = w&1, col-half nt2 = (w>>1)&1, K-half kh = w>>2.
    // A = bf16(feat1) hi-only; B = W2 hi+lo (2 MFMAs per K-step, 8 steps/wave).
    f32x16 acc2;
    #pragma unroll
    for (int r = 0; r < 16; ++r) acc2[r] = 0.f;
    const int m2   = w & 1;
    const int nt2  = (w >> 1) & 1;
    const int kh   = w >> 2;
    const int arow = m2*32 + l31;

    const short8v* W2H = (const short8v*)w2h;
    const short8v* W2L = (const short8v*)w2l;
    short8v bhc = W2H[(size_t)((kh*8)*2 + nt2)*64 + lane];
    short8v blc = W2L[(size_t)((kh*8)*2 + nt2)*64 + lane];
    #pragma unroll
    for (int i = 0; i < 8; ++i) {
        const int ks = kh*8 + i;
        short8v bhn = bhc, bln = blc;
        if (i + 1 < 8) {
            size_t nbase = (size_t)((ks + 1)*2 + nt2)*64 + lane;
            bhn = W2H[nbase];
            bln = W2L[nbase];
        }
        int blk  = (ks*2 + hs) ^ (arow & 31);
        short8v ah2 = *(const short8v*)&F1h[arow*256 + blk*8];
        acc2 = __builtin_amdgcn_mfma_f32_32x32x16_bf16(ah2, bhc, acc2, 0,0,0);
        acc2 = __builtin_amdgcn_mfma_f32_32x32x16_bf16(ah2, blc, acc2, 0,0,0);
        bhc = bhn; blc = bln;
    }

    // upper K-half waves deposit partials into Part (ring buf 2 region, now free)
    if (w >= 4) {
        #pragma unroll
        for (int r = 0; r < 16; ++r)
            Part[(w - 4)*1024 + r*64 + lane] = acc2[r];
    }
    __syncthreads();   // F1h reads done; partials visible

    // ---- epilogue2 (waves 0-3): combine K-halves, s_n = relu(feat2+b2).Wout ----
    if (w < 4) {
        const int   col2 = nt2*32 + l31;
        const float b2c  = b2[col2];
        const float woc  = Wout[col2];
        #pragma unroll
        for (int r = 0; r < 16; ++r) {
            float v2 = acc2[r] + Part[w*1024 + r*64 + lane];
            float v = fmaxf(v2 + b2c, 0.f) * woc;
            v += __shfl_xor(v, 1);
            v += __shfl_xor(v, 2);
            v += __shfl_xor(v, 4);
            v += __shfl_xor(v, 8);
            v += __shfl_xor(v, 16);
            if (l31 == 0) {
                int grow = m2*32 + (r & 3) + 8*(r >> 2) + 4*hs;
                s2p[nt2*64 + grow] = v;   // [colhalf][row]
            }
        }
    }
    __syncthreads();
    if (t < 64) srow[t] = s2p[t] + s2p[64 + t];
    __syncthreads();

    // ---- segmented sum over sorted batch, one atomic per run ----
    if (t < 64) {
        int node = n0 + t;
        int b = (node < N) ? batch[node] : -1;
        int pb = (t == 0) ? -2 : ((node - 1 < N) ? batch[node - 1] : -1);
        if (b >= 0 && b != pb) {
            float acc = 0.f;
            int j = t;
            while (j < 64 && (n0 + j) < N && batch[n0 + j] == b) { acc += srow[j]; ++j; }
            atomicAdd(&gf1d[b], acc);
        }
    }
}

__global__ void final_sigmoid(const float* __restrict__ gf1d, const float* __restrict__ bout,
                              float* __restrict__ out, int G)
{
    int g = blockIdx.x * 256 + threadIdx.x;
    if (g < G) out[g] = 1.f / (1.f + expf(-(gf1d[g] + bout[0])));
}

extern "C" void kernel_launch(void* const* d_in, const int* in_sizes, int n_in,
                              void* d_out, int out_size, void* d_ws, size_t ws_size,
                              hipStream_t stream)
{
    const float* h    = (const float*)d_in[0];
    const float* x    = (const float*)d_in[1];
    const int*   batch= (const int*)d_in[2];
    const float* W1   = (const float*)d_in[3];
    const float* b1   = (const float*)d_in[4];
    const float* W2   = (const float*)d_in[5];
    const float* b2   = (const float*)d_in[6];
    const float* Wout = (const float*)d_in[7];
    const float* bout = (const float*)d_in[8];
    float* out = (float*)d_out;

    const int N = in_sizes[2];
    const int G = out_size;

    // workspace layout (~305 KB total)
    char* ws = (char*)d_ws;
    float* gf1d = (float*)ws;                                  //   8,192 B
    float* zbuf = (float*)(ws + 8192);                         //   1,024 B (zeros)
    unsigned short* w1h = (unsigned short*)(ws + 9216);        // 229,376 B
    unsigned short* w2h = w1h + (size_t)W1P_SH8 * 8;           //  32,768 B
    unsigned short* w2l = w2h + (size_t)W2P_SH8 * 8;           //  32,768 B

    hipMemsetAsync(gf1d, 0, 9216, stream);   // gf accumulators + zero buffer
    pack_weights<<<(W1P_SH8 + W2P_SH8 + 255) / 256, 256, 0, stream>>>(W1, W2, w1h, w2h, w2l);
    fused_readout<<<(N + BM - 1) / BM, 512, 0, stream>>>(h, x, batch, w1h, w2h, w2l,
                                                         b1, b2, Wout, zbuf, gf1d, N);
    final_sigmoid<<<(G + 255) / 256, 256, 0, stream>>>(gf1d, bout, out, G);
}

// Round 17
// 168.804 us; speedup vs baseline: 1.2515x; 1.2515x over previous
//
#include <hip/hip_runtime.h>
#include <hip/hip_bf16.h>
#include <math.h>

// Fused GNN readout via bf16 MFMA (v_mfma_f32_32x32x16_bf16):
//   feat1 = relu(concat(h,x) @ W1 + b1)   [N,256]  GEMM1: K=400(pad 448), A=bf16 hi, B=W1 hi ONLY
//   feat2 = relu(feat1 @ W2 + b2)         [N,64]   GEMM2: K=256, A=bf16 hi, B=W2 hi+lo
//   s_n   = feat2 . Wout ; out = sigmoid(segment_sum(s_n) + bout)
// R17 = R15 (165us best) + ONE delta: A-fragment prefetch one SSTEP ahead.
//   R16 post-mortem: halving wave-area did NOT raise occupancy (27%) and
//   doubled B traffic -> reverted. R15's binder is the per-SSTEP serial chain
//   ds_read A (120cy) -> cvt -> MFMA with only 2 waves/SIMD. Fix: read A(s+1)
//   before MFMA(s) (+8 regs, 84->~95 arch, /3 cap 170 — no spill risk).
//   Counted-vmcnt discipline unchanged (margin >=4, never 0, no sched_barrier).

typedef __attribute__((ext_vector_type(8)))  short short8v;
typedef __attribute__((ext_vector_type(16))) float f32x16;

#define G_NUM 2048
#define HID 200
#define EMB 200
#define DIN 400
#define NH1 256
#define NH2 64
#define BM  64
#define NKS1 28        // bf16 K-steps (of 16) for GEMM1, K padded 400->448
#define NCH  7         // 7 chunks of 64 fp32 cols
#define NKS2 16        // K-steps for GEMM2 (K=256)

#define W1P_SH8 (NKS1*8*64)   // 14336 fragments (16B each), hi plane only
#define W2P_SH8 (NKS2*2*64)   // 2048

__device__ __forceinline__ unsigned short f2bf(float f) {
    union { float f; unsigned u; } v; v.f = f;
    unsigned r = v.u + 0x7fffu + ((v.u >> 16) & 1u);   // RNE
    return (unsigned short)(r >> 16);
}
__device__ __forceinline__ float bf2f(unsigned short b) {
    union { unsigned u; float f; } v; v.u = ((unsigned)b) << 16;
    return v.f;
}
// 8 fp32 -> 8 bf16 (RNE) via packed converts
__device__ __forceinline__ short8v cvt8(float4 a, float4 b) {
    union { __hip_bfloat162 q[4]; short8v s8; } u;
    u.q[0] = __float22bfloat162_rn(make_float2(a.x, a.y));
    u.q[1] = __float22bfloat162_rn(make_float2(a.z, a.w));
    u.q[2] = __float22bfloat162_rn(make_float2(b.x, b.y));
    u.q[3] = __float22bfloat162_rn(make_float2(b.z, b.w));
    return u.s8;
}

// Pre-pack W1 (hi only) / W2 (hi+lo) into MFMA-fragment order.
// Fragment (ks, ntile, lane) holds 8 bf16: B[k0+j][col], k0=ks*16+(lane>>5)*8,
// col=ntile*32+(lane&31). Contiguous-8 k in BOTH A and B => any consistent
// hw k-permutation cancels in the dot product.
__global__ void pack_weights(const float* __restrict__ W1, const float* __restrict__ W2,
                             unsigned short* __restrict__ w1h,
                             unsigned short* __restrict__ w2h, unsigned short* __restrict__ w2l)
{
    int idx = blockIdx.x * 256 + threadIdx.x;
    if (idx < W1P_SH8) {
        int l  = idx & 63;
        int nt = (idx >> 6) & 7;
        int ks = idx >> 9;
        int col = nt * 32 + (l & 31);
        int k0  = ks * 16 + (l >> 5) * 8;
        short8v H;
        #pragma unroll
        for (int j = 0; j < 8; ++j) {
            int k = k0 + j;
            H[j] = (short)f2bf((k < DIN) ? W1[(size_t)k * NH1 + col] : 0.f);
        }
        ((short8v*)w1h)[idx] = H;
    } else if (idx < W1P_SH8 + W2P_SH8) {
        int i2 = idx - W1P_SH8;
        int l  = i2 & 63;
        int nt = (i2 >> 6) & 1;
        int ks = i2 >> 7;
        int col = nt * 32 + (l & 31);
        int k0  = ks * 16 + (l >> 5) * 8;
        short8v H, L;
        #pragma unroll
        for (int j = 0; j < 8; ++j) {
            float v = W2[(size_t)(k0 + j) * NH2 + col];
            unsigned short hh = f2bf(v);
            H[j] = (short)hh;
            L[j] = (short)f2bf(v - bf2f(hh));
        }
        ((short8v*)w2h)[i2] = H;
        ((short8v*)w2l)[i2] = L;
    }
}

__launch_bounds__(256, 3)
__global__ void fused_readout(const float* __restrict__ h, const float* __restrict__ x,
                              const int* __restrict__ batch,
                              const unsigned short* __restrict__ w1h,
                              const unsigned short* __restrict__ w2h, const unsigned short* __restrict__ w2l,
                              const float* __restrict__ b1, const float* __restrict__ b2,
                              const float* __restrict__ Wout, const float* __restrict__ zbuf,
                              float* __restrict__ gf1d, int N)
{
    // 49152 B LDS, time-multiplexed (R8/R14 layout):
    //   [GEMM1] A fp32 ring: 3 bufs x [64 rows][64 fp32] = 49152 B
    //           (row stride 256 B; 16B-granule XOR swizzle c16 ^= row&15 applied
    //            on the GLOBAL SOURCE; LDS dest linear for global_load_lds)
    //   [GEMM2] F1h [64][256] bf16 = 32768 B (overlaps ring bufs 0-1)
    //   [pool ] s2p[2][64] f32 at 0, srow[64] f32 at byte 512
    __shared__ __align__(16) char lds[49152];
    unsigned short* F1h = (unsigned short*)lds;
    float* s2p  = (float*)lds;          // 128 floats
    float* srow = (float*)(lds + 512);  // 64 floats

    const int t    = threadIdx.x;
    const int lane = t & 63;
    const int w    = t >> 6;
    const int n0   = blockIdx.x * BM;
    const int l31  = lane & 31;
    const int hs   = lane >> 5;         // k-half select

    const short8v* W1H = (const short8v*)w1h;

    f32x16 acc00, acc01, acc10, acc11;
    #pragma unroll
    for (int r = 0; r < 16; ++r) { acc00[r] = 0.f; acc01[r] = 0.f; acc10[r] = 0.f; acc11[r] = 0.f; }

    // ---- helpers ----
    // issue 4 global_load_lds covering this wave's 16 rows of chunk CH into ring buffer BUF
    // dest: linear  BUF*16384 + brow*256 + lane*16
    // src : per-lane, pre-swizzled col16 = (lane&15) ^ (row&15); OOB -> zbuf
    #define AISSUE(CH, BUF) do {                                               \
        _Pragma("unroll")                                                      \
        for (int ii = 0; ii < 4; ++ii) {                                       \
            int brow = w*16 + ii*4;                                            \
            int row  = brow + (lane >> 4);                                     \
            int node = n0 + row;                                               \
            int colf = (CH)*64 + (((lane & 15) ^ (row & 15)) << 2);            \
            const float* src;                                                  \
            if (node >= N || colf >= DIN) src = zbuf + (lane & 15)*4;          \
            else if (colf < HID)          src = h + (size_t)node*HID + colf;   \
            else                          src = x + (size_t)node*EMB + (colf - HID); \
            __builtin_amdgcn_global_load_lds(                                  \
                (const __attribute__((address_space(1))) unsigned*)src,        \
                (__attribute__((address_space(3))) unsigned*)(lds + (BUF)*16384 + brow*256 + lane*16), \
                16, 0, 0);                                                     \
        } } while (0)

    // A fragment: row ROW, logical col16 pair {S*4+hs*2, +1} of ring buffer (byte base HB)
    #define AFRAG(HB, S, ROW)                                                  \
        cvt8(*(const float4*)(lds + (HB) + (ROW)*256 + ((((S)*4 + hs*2)     ^ ((ROW) & 15)) << 4)), \
             *(const float4*)(lds + (HB) + (ROW)*256 + ((((S)*4 + hs*2 + 1) ^ ((ROW) & 15)) << 4)))

    // load one k-step's 2 B hi-fragments into named regs
    #define BLOAD2(KS, H0, H1) do {                                            \
        size_t nb_ = ((size_t)((KS)*8 + w*2))*64 + lane;                       \
        H0 = W1H[nb_]; H1 = W1H[nb_ + 64]; } while (0)

    // ---- prologue: A chunks 0,1 in flight; B ksteps 0,1 in regs-in-flight ----
    AISSUE(0, 0);
    AISSUE(1, 1);
    short8v c0h0, c0h1;    // B(ks)   — consumed this k-step
    short8v c1h0, c1h1;    // B(ks+1)
    BLOAD2(0, c0h0, c0h1);
    BLOAD2(1, c1h0, c1h1);

    // ================= GEMM1: 7 chunks x 4 k-steps, counted-vmcnt + A-prefetch =================
    #pragma unroll
    for (int c = 0; c < NCH; ++c) {
        // Loads newer than A(c) at this point (issue order: A0,A1,Bpro(4),
        // then per chunk: A(c+2):4 + B:8):
        //   c=0: 8   c=1: 16   c>=2: 20 (16 at c=6).
        // Counted waits with margin >=4 — never 0, never exact.
        if (c == 0) { asm volatile("s_waitcnt vmcnt(4)"  ::: "memory"); }
        else        { asm volatile("s_waitcnt vmcnt(12)" ::: "memory"); }
        __builtin_amdgcn_s_barrier();   // all waves' A(c) complete; ring (c+2)%3 free
        if (c + 2 < NCH) AISSUE(c + 2, (c + 2) % 3);

        const int hb = (c % 3) * 16384;
        // blocking read of this chunk's s=0 A fragments
        short8v a0 = AFRAG(hb, 0, l31);
        short8v a1 = AFRAG(hb, 0, 32 + l31);
        #pragma unroll
        for (int s = 0; s < 4; ++s) {
            const int ks = c * 4 + s;
            // prefetch B(ks+2) (depth 2; dummy ks=0 at tail)
            short8v n2h0, n2h1;
            BLOAD2((ks + 2 < NKS1) ? ks + 2 : 0, n2h0, n2h1);
            // current A fragments (read at chunk top or previous SSTEP)
            short8v p0 = a0, p1 = a1;
            // prefetch A(s+1) — ds_read+cvt hidden under this step's MFMAs
            if (s + 1 < 4) {
                a0 = AFRAG(hb, s + 1, l31);
                a1 = AFRAG(hb, s + 1, 32 + l31);
            }
            acc00 = __builtin_amdgcn_mfma_f32_32x32x16_bf16(p0, c0h0, acc00, 0,0,0);
            acc01 = __builtin_amdgcn_mfma_f32_32x32x16_bf16(p0, c0h1, acc01, 0,0,0);
            acc10 = __builtin_amdgcn_mfma_f32_32x32x16_bf16(p1, c0h0, acc10, 0,0,0);
            acc11 = __builtin_amdgcn_mfma_f32_32x32x16_bf16(p1, c0h1, acc11, 0,0,0);
            // rotate B pipeline
            c0h0 = c1h0; c0h1 = c1h1;
            c1h0 = n2h0; c1h1 = n2h1;
        }
    }
    #undef BLOAD2
    #undef AFRAG
    #undef AISSUE

    __syncthreads();   // all ring reads done; F1h may overwrite bufs 0-1

    // ---- epilogue1: bias + relu + bf16 (hi only) -> F1h (XOR-swizzled) ----
    // C/D layout: col = lane&31, row = (r&3) + 8*(r>>2) + 4*(lane>>5)
    const float b1c0 = b1[w*64 + l31];
    const float b1c1 = b1[w*64 + 32 + l31];
#define EPI1(ACC, MI, NI) do {                                            \
        int gcol = w*64 + (NI)*32 + l31;                                  \
        float bb = (NI) ? b1c1 : b1c0;                                    \
        _Pragma("unroll")                                                 \
        for (int r = 0; r < 16; ++r) {                                    \
            int grow = (MI)*32 + (r & 3) + 8*(r >> 2) + 4*hs;             \
            float v = fmaxf(ACC[r] + bb, 0.f);                            \
            int phys = grow*256 + (((gcol >> 3) ^ (grow & 31)) << 3) + (gcol & 7); \
            F1h[phys] = f2bf(v);                                          \
        } } while (0)
    EPI1(acc00, 0, 0); EPI1(acc01, 0, 1); EPI1(acc10, 1, 0); EPI1(acc11, 1, 1);
#undef EPI1
    __syncthreads();

    // ================= GEMM2: feat2 = relu(feat1 @ W2 + b2) =================
    // A = bf16(feat1) hi-only; B = W2 hi+lo (2 MFMAs per K-step).
    f32x16 acc2;
    #pragma unroll
    for (int r = 0; r < 16; ++r) acc2[r] = 0.f;
    const int m2   = w >> 1;      // node-row half
    const int nt2  = w & 1;       // col half
    const int arow = m2*32 + l31;

    const short8v* W2H = (const short8v*)w2h;
    const short8v* W2L = (const short8v*)w2l;
    short8v bhc = W2H[(size_t)nt2*64 + lane];
    short8v blc = W2L[(size_t)nt2*64 + lane];
    #pragma unroll
    for (int ks = 0; ks < NKS2; ++ks) {
        short8v bhn = bhc, bln = blc;
        if (ks + 1 < NKS2) {
            size_t nbase = (size_t)((ks + 1)*2 + nt2)*64 + lane;
            bhn = W2H[nbase];
            bln = W2L[nbase];
        }
        int blk  = (ks*2 + hs) ^ (arow & 31);
        short8v ah2 = *(const short8v*)&F1h[arow*256 + blk*8];
        acc2 = __builtin_amdgcn_mfma_f32_32x32x16_bf16(ah2, bhc, acc2, 0,0,0);
        acc2 = __builtin_amdgcn_mfma_f32_32x32x16_bf16(ah2, blc, acc2, 0,0,0);
        bhc = bhn; blc = bln;
    }
    __syncthreads();   // all F1 reads done; s2p/srow may now overwrite LDS

    // ---- epilogue2: s_n = relu(feat2 + b2) . Wout, 32-col shfl reduce ----
    {
        const int   col2 = nt2*32 + l31;
        const float b2c  = b2[col2];
        const float woc  = Wout[col2];
        #pragma unroll
        for (int r = 0; r < 16; ++r) {
            float v = fmaxf(acc2[r] + b2c, 0.f) * woc;
            v += __shfl_xor(v, 1);
            v += __shfl_xor(v, 2);
            v += __shfl_xor(v, 4);
            v += __shfl_xor(v, 8);
            v += __shfl_xor(v, 16);
            if (l31 == 0) {
                int grow = m2*32 + (r & 3) + 8*(r >> 2) + 4*hs;
                s2p[nt2*64 + grow] = v;   // [colhalf][row]
            }
        }
    }
    __syncthreads();
    if (t < 64) srow[t] = s2p[t] + s2p[64 + t];
    __syncthreads();

    // ---- segmented sum over sorted batch, one atomic per run ----
    if (t < 64) {
        int node = n0 + t;
        int b = (node < N) ? batch[node] : -1;
        int pb = (t == 0) ? -2 : ((node - 1 < N) ? batch[node - 1] : -1);
        if (b >= 0 && b != pb) {
            float acc = 0.f;
            int j = t;
            while (j < 64 && (n0 + j) < N && batch[n0 + j] == b) { acc += srow[j]; ++j; }
            atomicAdd(&gf1d[b], acc);
        }
    }
}

__global__ void final_sigmoid(const float* __restrict__ gf1d, const float* __restrict__ bout,
                              float* __restrict__ out, int G)
{
    int g = blockIdx.x * 256 + threadIdx.x;
    if (g < G) out[g] = 1.f / (1.f + expf(-(gf1d[g] + bout[0])));
}

extern "C" void kernel_launch(void* const* d_in, const int* in_sizes, int n_in,
                              void* d_out, int out_size, void* d_ws, size_t ws_size,
                              hipStream_t stream)
{
    const float* h    = (const float*)d_in[0];
    const float* x    = (const float*)d_in[1];
    const int*   batch= (const int*)d_in[2];
    const float* W1   = (const float*)d_in[3];
    const float* b1   = (const float*)d_in[4];
    const float* W2   = (const float*)d_in[5];
    const float* b2   = (const float*)d_in[6];
    const float* Wout = (const float*)d_in[7];
    const float* bout = (const float*)d_in[8];
    float* out = (float*)d_out;

    const int N = in_sizes[2];
    const int G = out_size;

    // workspace layout (~305 KB total)
    char* ws = (char*)d_ws;
    float* gf1d = (float*)ws;                                  //   8,192 B
    float* zbuf = (float*)(ws + 8192);                         //   1,024 B (zeros)
    unsigned short* w1h = (unsigned short*)(ws + 9216);        // 229,376 B
    unsigned short* w2h = w1h + (size_t)W1P_SH8 * 8;           //  32,768 B
    unsigned short* w2l = w2h + (size_t)W2P_SH8 * 8;           //  32,768 B

    hipMemsetAsync(gf1d, 0, 9216, stream);   // gf accumulators + zero buffer
    pack_weights<<<(W1P_SH8 + W2P_SH8 + 255) / 256, 256, 0, stream>>>(W1, W2, w1h, w2h, w2l);
    fused_readout<<<(N + BM - 1) / BM, 256, 0, stream>>>(h, x, batch, w1h, w2h, w2l,
                                                         b1, b2, Wout, zbuf, gf1d, N);
    final_sigmoid<<<(G + 255) / 256, 256, 0, stream>>>(gf1d, bout, out, G);
}

// Round 18
// 160.512 us; speedup vs baseline: 1.3161x; 1.0517x over previous
//
#include <hip/hip_runtime.h>
#include <hip/hip_bf16.h>
#include <math.h>

// Fused GNN readout via bf16 MFMA (v_mfma_f32_32x32x16_bf16):
//   feat1 = relu(concat(h,x) @ W1 + b1)   [N,256]  GEMM1: K=400(pad 448), A=bf16 hi, B=W1 hi ONLY
//   feat2 = relu(feat1 @ W2 + b2)         [N,64]   GEMM2: K=256, A=bf16 hi, B=W2 hi ONLY
//   s_n   = feat2 . Wout ; out = sigmoid(segment_sum(s_n) + bout)
// R18 = R15 (165us best) + B-latency attack (A-side exonerated by R17-neutral):
//   - GEMM1 B register pipe depth 2->3 (+8 regs): ~3 k-steps of cover vs
//     ~250-300cy L2 latency (depth-2 gave only ~180cy -> per-SSTEP stall).
//   - W2 hi-only (error adds in quadrature to dominant feat1-bf16 term;
//     predicted absmax ~2.5e-6 < 7.8e-6 thr): GEMM2 1 MFMA/step.
//   - GEMM2 B pipe depth 4, first 4 frags issued during EPI1 (latency under
//     repack+barrier).
//   Counted-vmcnt discipline unchanged: c=0 vmcnt(6), else vmcnt(12) — exact
//   counts 10/16-20, margin >=4, never 0, no sched_barrier (R13 lesson).

typedef __attribute__((ext_vector_type(8)))  short short8v;
typedef __attribute__((ext_vector_type(16))) float f32x16;

#define G_NUM 2048
#define HID 200
#define EMB 200
#define DIN 400
#define NH1 256
#define NH2 64
#define BM  64
#define NKS1 28        // bf16 K-steps (of 16) for GEMM1, K padded 400->448
#define NCH  7         // 7 chunks of 64 fp32 cols
#define NKS2 16        // K-steps for GEMM2 (K=256)

#define W1P_SH8 (NKS1*8*64)   // 14336 fragments (16B each), hi plane only
#define W2P_SH8 (NKS2*2*64)   // 2048

__device__ __forceinline__ unsigned short f2bf(float f) {
    union { float f; unsigned u; } v; v.f = f;
    unsigned r = v.u + 0x7fffu + ((v.u >> 16) & 1u);   // RNE
    return (unsigned short)(r >> 16);
}
__device__ __forceinline__ float bf2f(unsigned short b) {
    union { unsigned u; float f; } v; v.u = ((unsigned)b) << 16;
    return v.f;
}
// 8 fp32 -> 8 bf16 (RNE) via packed converts
__device__ __forceinline__ short8v cvt8(float4 a, float4 b) {
    union { __hip_bfloat162 q[4]; short8v s8; } u;
    u.q[0] = __float22bfloat162_rn(make_float2(a.x, a.y));
    u.q[1] = __float22bfloat162_rn(make_float2(a.z, a.w));
    u.q[2] = __float22bfloat162_rn(make_float2(b.x, b.y));
    u.q[3] = __float22bfloat162_rn(make_float2(b.z, b.w));
    return u.s8;
}

// Pre-pack W1 (hi only) / W2 (hi, lo packed but lo unused) into MFMA-fragment
// order. Fragment (ks, ntile, lane) holds 8 bf16: B[k0+j][col],
// k0=ks*16+(lane>>5)*8, col=ntile*32+(lane&31). Contiguous-8 k in BOTH A and
// B => any consistent hw k-permutation cancels in the dot product.
__global__ void pack_weights(const float* __restrict__ W1, const float* __restrict__ W2,
                             unsigned short* __restrict__ w1h,
                             unsigned short* __restrict__ w2h, unsigned short* __restrict__ w2l)
{
    int idx = blockIdx.x * 256 + threadIdx.x;
    if (idx < W1P_SH8) {
        int l  = idx & 63;
        int nt = (idx >> 6) & 7;
        int ks = idx >> 9;
        int col = nt * 32 + (l & 31);
        int k0  = ks * 16 + (l >> 5) * 8;
        short8v H;
        #pragma unroll
        for (int j = 0; j < 8; ++j) {
            int k = k0 + j;
            H[j] = (short)f2bf((k < DIN) ? W1[(size_t)k * NH1 + col] : 0.f);
        }
        ((short8v*)w1h)[idx] = H;
    } else if (idx < W1P_SH8 + W2P_SH8) {
        int i2 = idx - W1P_SH8;
        int l  = i2 & 63;
        int nt = (i2 >> 6) & 1;
        int ks = i2 >> 7;
        int col = nt * 32 + (l & 31);
        int k0  = ks * 16 + (l >> 5) * 8;
        short8v H, L;
        #pragma unroll
        for (int j = 0; j < 8; ++j) {
            float v = W2[(size_t)(k0 + j) * NH2 + col];
            unsigned short hh = f2bf(v);
            H[j] = (short)hh;
            L[j] = (short)f2bf(v - bf2f(hh));
        }
        ((short8v*)w2h)[i2] = H;
        ((short8v*)w2l)[i2] = L;
    }
}

__launch_bounds__(256, 3)
__global__ void fused_readout(const float* __restrict__ h, const float* __restrict__ x,
                              const int* __restrict__ batch,
                              const unsigned short* __restrict__ w1h,
                              const unsigned short* __restrict__ w2h,
                              const float* __restrict__ b1, const float* __restrict__ b2,
                              const float* __restrict__ Wout, const float* __restrict__ zbuf,
                              float* __restrict__ gf1d, int N)
{
    // 49152 B LDS, time-multiplexed (R8/R14 layout):
    //   [GEMM1] A fp32 ring: 3 bufs x [64 rows][64 fp32] = 49152 B
    //           (row stride 256 B; 16B-granule XOR swizzle c16 ^= row&15 applied
    //            on the GLOBAL SOURCE; LDS dest linear for global_load_lds)
    //   [GEMM2] F1h [64][256] bf16 = 32768 B (overlaps ring bufs 0-1)
    //   [pool ] s2p[2][64] f32 at 0, srow[64] f32 at byte 512
    __shared__ __align__(16) char lds[49152];
    unsigned short* F1h = (unsigned short*)lds;
    float* s2p  = (float*)lds;          // 128 floats
    float* srow = (float*)(lds + 512);  // 64 floats

    const int t    = threadIdx.x;
    const int lane = t & 63;
    const int w    = t >> 6;
    const int n0   = blockIdx.x * BM;
    const int l31  = lane & 31;
    const int hs   = lane >> 5;         // k-half select

    const short8v* W1H = (const short8v*)w1h;

    f32x16 acc00, acc01, acc10, acc11;
    #pragma unroll
    for (int r = 0; r < 16; ++r) { acc00[r] = 0.f; acc01[r] = 0.f; acc10[r] = 0.f; acc11[r] = 0.f; }

    // ---- helpers ----
    // issue 4 global_load_lds covering this wave's 16 rows of chunk CH into ring buffer BUF
    // dest: linear  BUF*16384 + brow*256 + lane*16
    // src : per-lane, pre-swizzled col16 = (lane&15) ^ (row&15); OOB -> zbuf
    #define AISSUE(CH, BUF) do {                                               \
        _Pragma("unroll")                                                      \
        for (int ii = 0; ii < 4; ++ii) {                                       \
            int brow = w*16 + ii*4;                                            \
            int row  = brow + (lane >> 4);                                     \
            int node = n0 + row;                                               \
            int colf = (CH)*64 + (((lane & 15) ^ (row & 15)) << 2);            \
            const float* src;                                                  \
            if (node >= N || colf >= DIN) src = zbuf + (lane & 15)*4;          \
            else if (colf < HID)          src = h + (size_t)node*HID + colf;   \
            else                          src = x + (size_t)node*EMB + (colf - HID); \
            __builtin_amdgcn_global_load_lds(                                  \
                (const __attribute__((address_space(1))) unsigned*)src,        \
                (__attribute__((address_space(3))) unsigned*)(lds + (BUF)*16384 + brow*256 + lane*16), \
                16, 0, 0);                                                     \
        } } while (0)

    // A fragment: row ROW, logical col16 pair {S*4+hs*2, +1} of ring buffer (byte base HB)
    #define AFRAG(HB, S, ROW)                                                  \
        cvt8(*(const float4*)(lds + (HB) + (ROW)*256 + ((((S)*4 + hs*2)     ^ ((ROW) & 15)) << 4)), \
             *(const float4*)(lds + (HB) + (ROW)*256 + ((((S)*4 + hs*2 + 1) ^ ((ROW) & 15)) << 4)))

    // load one k-step's 2 B hi-fragments into named regs
    #define BLOAD2(KS, H0, H1) do {                                            \
        size_t nb_ = ((size_t)((KS)*8 + w*2))*64 + lane;                       \
        H0 = W1H[nb_]; H1 = W1H[nb_ + 64]; } while (0)

    // ---- prologue: A chunks 0,1 in flight; B pipe filled to depth 3 ----
    AISSUE(0, 0);
    AISSUE(1, 1);
    short8v b0h0, b0h1, b1h0, b1h1, b2h0, b2h1;
    BLOAD2(0, b0h0, b0h1);
    BLOAD2(1, b1h0, b1h1);
    BLOAD2(2, b2h0, b2h1);

    // ================= GEMM1: 7 chunks x 4 k-steps, counted-vmcnt, B depth 3 =================
    #pragma unroll
    for (int c = 0; c < NCH; ++c) {
        // Loads newer than A(c) at this point (issue order: A0:4, A1:4, Bpro:6,
        // then per chunk: A(c+2):4 + B:8):
        //   c=0: 10   c=1: 18   c=2..5: 20   c=6: 16.
        // Counted waits with margin >=4 — never 0, never exact.
        if (c == 0) { asm volatile("s_waitcnt vmcnt(6)"  ::: "memory"); }
        else        { asm volatile("s_waitcnt vmcnt(12)" ::: "memory"); }
        __builtin_amdgcn_s_barrier();   // all waves' A(c) complete; ring (c+2)%3 free
        if (c + 2 < NCH) AISSUE(c + 2, (c + 2) % 3);

        const int hb = (c % 3) * 16384;
        #pragma unroll
        for (int s = 0; s < 4; ++s) {
            const int ks = c * 4 + s;
            // prefetch B(ks+3) (depth 3; dummy ks=0 at tail)
            short8v nh0, nh1;
            BLOAD2((ks + 3 < NKS1) ? ks + 3 : 0, nh0, nh1);
            // A fragments (LDS ring) + convert
            short8v ah0 = AFRAG(hb, s, l31);
            short8v ah1 = AFRAG(hb, s, 32 + l31);
            acc00 = __builtin_amdgcn_mfma_f32_32x32x16_bf16(ah0, b0h0, acc00, 0,0,0);
            acc01 = __builtin_amdgcn_mfma_f32_32x32x16_bf16(ah0, b0h1, acc01, 0,0,0);
            acc10 = __builtin_amdgcn_mfma_f32_32x32x16_bf16(ah1, b0h0, acc10, 0,0,0);
            acc11 = __builtin_amdgcn_mfma_f32_32x32x16_bf16(ah1, b0h1, acc11, 0,0,0);
            // rotate 3-deep B pipeline
            b0h0 = b1h0; b0h1 = b1h1;
            b1h0 = b2h0; b1h1 = b2h1;
            b2h0 = nh0;  b2h1 = nh1;
        }
    }
    #undef BLOAD2
    #undef AFRAG
    #undef AISSUE

    __syncthreads();   // all ring reads done; F1h may overwrite bufs 0-1

    // ---- GEMM2 B preload (issued here so L2 latency hides under EPI1+barrier) ----
    const int m2   = w >> 1;      // node-row half
    const int nt2  = w & 1;       // col half
    const short8v* W2H = (const short8v*)w2h;
    short8v g0 = W2H[(size_t)(0*2 + nt2)*64 + lane];
    short8v g1 = W2H[(size_t)(1*2 + nt2)*64 + lane];
    short8v g2 = W2H[(size_t)(2*2 + nt2)*64 + lane];
    short8v g3 = W2H[(size_t)(3*2 + nt2)*64 + lane];

    // ---- epilogue1: bias + relu + bf16 (hi only) -> F1h (XOR-swizzled) ----
    // C/D layout: col = lane&31, row = (r&3) + 8*(r>>2) + 4*(lane>>5)
    const float b1c0 = b1[w*64 + l31];
    const float b1c1 = b1[w*64 + 32 + l31];
#define EPI1(ACC, MI, NI) do {                                            \
        int gcol = w*64 + (NI)*32 + l31;                                  \
        float bb = (NI) ? b1c1 : b1c0;                                    \
        _Pragma("unroll")                                                 \
        for (int r = 0; r < 16; ++r) {                                    \
            int grow = (MI)*32 + (r & 3) + 8*(r >> 2) + 4*hs;             \
            float v = fmaxf(ACC[r] + bb, 0.f);                            \
            int phys = grow*256 + (((gcol >> 3) ^ (grow & 31)) << 3) + (gcol & 7); \
            F1h[phys] = f2bf(v);                                          \
        } } while (0)
    EPI1(acc00, 0, 0); EPI1(acc01, 0, 1); EPI1(acc10, 1, 0); EPI1(acc11, 1, 1);
#undef EPI1
    __syncthreads();

    // ================= GEMM2: feat2 = relu(feat1 @ W2 + b2) =================
    // A = bf16(feat1) hi-only; B = W2 hi-only (1 MFMA/step), pipe depth 4.
    f32x16 acc2;
    #pragma unroll
    for (int r = 0; r < 16; ++r) acc2[r] = 0.f;
    const int arow = m2*32 + l31;

    #pragma unroll
    for (int ks = 0; ks < NKS2; ++ks) {
        // prefetch B(ks+4) (depth 4; dummy index 0 at tail)
        short8v gn = W2H[(size_t)(((ks + 4 < NKS2) ? ks + 4 : 0)*2 + nt2)*64 + lane];
        int blk  = (ks*2 + hs) ^ (arow & 31);
        short8v ah2 = *(const short8v*)&F1h[arow*256 + blk*8];
        acc2 = __builtin_amdgcn_mfma_f32_32x32x16_bf16(ah2, g0, acc2, 0,0,0);
        g0 = g1; g1 = g2; g2 = g3; g3 = gn;
    }
    __syncthreads();   // all F1 reads done; s2p/srow may now overwrite LDS

    // ---- epilogue2: s_n = relu(feat2 + b2) . Wout, 32-col shfl reduce ----
    {
        const int   col2 = nt2*32 + l31;
        const float b2c  = b2[col2];
        const float woc  = Wout[col2];
        #pragma unroll
        for (int r = 0; r < 16; ++r) {
            float v = fmaxf(acc2[r] + b2c, 0.f) * woc;
            v += __shfl_xor(v, 1);
            v += __shfl_xor(v, 2);
            v += __shfl_xor(v, 4);
            v += __shfl_xor(v, 8);
            v += __shfl_xor(v, 16);
            if (l31 == 0) {
                int grow = m2*32 + (r & 3) + 8*(r >> 2) + 4*hs;
                s2p[nt2*64 + grow] = v;   // [colhalf][row]
            }
        }
    }
    __syncthreads();
    if (t < 64) srow[t] = s2p[t] + s2p[64 + t];
    __syncthreads();

    // ---- segmented sum over sorted batch, one atomic per run ----
    if (t < 64) {
        int node = n0 + t;
        int b = (node < N) ? batch[node] : -1;
        int pb = (t == 0) ? -2 : ((node - 1 < N) ? batch[node - 1] : -1);
        if (b >= 0 && b != pb) {
            float acc = 0.f;
            int j = t;
            while (j < 64 && (n0 + j) < N && batch[n0 + j] == b) { acc += srow[j]; ++j; }
            atomicAdd(&gf1d[b], acc);
        }
    }
}

__global__ void final_sigmoid(const float* __restrict__ gf1d, const float* __restrict__ bout,
                              float* __restrict__ out, int G)
{
    int g = blockIdx.x * 256 + threadIdx.x;
    if (g < G) out[g] = 1.f / (1.f + expf(-(gf1d[g] + bout[0])));
}

extern "C" void kernel_launch(void* const* d_in, const int* in_sizes, int n_in,
                              void* d_out, int out_size, void* d_ws, size_t ws_size,
                              hipStream_t stream)
{
    const float* h    = (const float*)d_in[0];
    const float* x    = (const float*)d_in[1];
    const int*   batch= (const int*)d_in[2];
    const float* W1   = (const float*)d_in[3];
    const float* b1   = (const float*)d_in[4];
    const float* W2   = (const float*)d_in[5];
    const float* b2   = (const float*)d_in[6];
    const float* Wout = (const float*)d_in[7];
    const float* bout = (const float*)d_in[8];
    float* out = (float*)d_out;

    const int N = in_sizes[2];
    const int G = out_size;

    // workspace layout (~305 KB total)
    char* ws = (char*)d_ws;
    float* gf1d = (float*)ws;                                  //   8,192 B
    float* zbuf = (float*)(ws + 8192);                         //   1,024 B (zeros)
    unsigned short* w1h = (unsigned short*)(ws + 9216);        // 229,376 B
    unsigned short* w2h = w1h + (size_t)W1P_SH8 * 8;           //  32,768 B
    unsigned short* w2l = w2h + (size_t)W2P_SH8 * 8;           //  32,768 B (packed, unused)

    hipMemsetAsync(gf1d, 0, 9216, stream);   // gf accumulators + zero buffer
    pack_weights<<<(W1P_SH8 + W2P_SH8 + 255) / 256, 256, 0, stream>>>(W1, W2, w1h, w2h, w2l);
    fused_readout<<<(N + BM - 1) / BM, 256, 0, stream>>>(h, x, batch, w1h, w2h,
                                                         b1, b2, Wout, zbuf, gf1d, N);
    final_sigmoid<<<(G + 255) / 256, 256, 0, stream>>>(gf1d, bout, out, G);
}

// Round 20
// 124.207 us; speedup vs baseline: 1.7008x; 1.2923x over previous
//
#include <hip/hip_runtime.h>
#include <hip/hip_bf16.h>
#include <math.h>

// Fused GNN readout via bf16 MFMA (v_mfma_f32_32x32x16_bf16):
//   feat1 = relu(concat(h,x) @ W1 + b1)   [N,256]  GEMM1: K=400(pad 448), A=bf16 hi, B=W1 hi ONLY
//   feat2 = relu(feat1 @ W2 + b2)         [N,64]   GEMM2: K=256, A=bf16 hi, B=W2 hi ONLY
//   s_n   = feat2 . Wout ; out = sigmoid(segment_sum(s_n) + bout)
// R20 = R19 + divergent-shuffle fix:
//   R19's __shfl(P, e-1) was INSIDE the head-only branch; source lane e-1
//   (run end) is not a head -> inactive -> ds_bpermute reads undefined data.
//   Fix: all 64 lanes execute the shuffle (e defined for every lane, e-1 in
//   [0,63]); only the atomicAdd stays predicated. Rest identical to R18/R19.

typedef __attribute__((ext_vector_type(8)))  short short8v;
typedef __attribute__((ext_vector_type(16))) float f32x16;

#define G_NUM 2048
#define HID 200
#define EMB 200
#define DIN 400
#define NH1 256
#define NH2 64
#define BM  64
#define NKS1 28        // bf16 K-steps (of 16) for GEMM1, K padded 400->448
#define NCH  7         // 7 chunks of 64 fp32 cols
#define NKS2 16        // K-steps for GEMM2 (K=256)

#define W1P_SH8 (NKS1*8*64)   // 14336 fragments (16B each), hi plane only
#define W2P_SH8 (NKS2*2*64)   // 2048

__device__ __forceinline__ unsigned short f2bf(float f) {
    union { float f; unsigned u; } v; v.f = f;
    unsigned r = v.u + 0x7fffu + ((v.u >> 16) & 1u);   // RNE
    return (unsigned short)(r >> 16);
}
__device__ __forceinline__ float bf2f(unsigned short b) {
    union { unsigned u; float f; } v; v.u = ((unsigned)b) << 16;
    return v.f;
}
// 8 fp32 -> 8 bf16 (RNE) via packed converts
__device__ __forceinline__ short8v cvt8(float4 a, float4 b) {
    union { __hip_bfloat162 q[4]; short8v s8; } u;
    u.q[0] = __float22bfloat162_rn(make_float2(a.x, a.y));
    u.q[1] = __float22bfloat162_rn(make_float2(a.z, a.w));
    u.q[2] = __float22bfloat162_rn(make_float2(b.x, b.y));
    u.q[3] = __float22bfloat162_rn(make_float2(b.z, b.w));
    return u.s8;
}

// Pre-pack W1 (hi only) / W2 (hi, lo packed but lo unused) into MFMA-fragment
// order. Fragment (ks, ntile, lane) holds 8 bf16: B[k0+j][col],
// k0=ks*16+(lane>>5)*8, col=ntile*32+(lane&31). Contiguous-8 k in BOTH A and
// B => any consistent hw k-permutation cancels in the dot product.
__global__ void pack_weights(const float* __restrict__ W1, const float* __restrict__ W2,
                             unsigned short* __restrict__ w1h,
                             unsigned short* __restrict__ w2h, unsigned short* __restrict__ w2l)
{
    int idx = blockIdx.x * 256 + threadIdx.x;
    if (idx < W1P_SH8) {
        int l  = idx & 63;
        int nt = (idx >> 6) & 7;
        int ks = idx >> 9;
        int col = nt * 32 + (l & 31);
        int k0  = ks * 16 + (l >> 5) * 8;
        short8v H;
        #pragma unroll
        for (int j = 0; j < 8; ++j) {
            int k = k0 + j;
            H[j] = (short)f2bf((k < DIN) ? W1[(size_t)k * NH1 + col] : 0.f);
        }
        ((short8v*)w1h)[idx] = H;
    } else if (idx < W1P_SH8 + W2P_SH8) {
        int i2 = idx - W1P_SH8;
        int l  = i2 & 63;
        int nt = (i2 >> 6) & 1;
        int ks = i2 >> 7;
        int col = nt * 32 + (l & 31);
        int k0  = ks * 16 + (l >> 5) * 8;
        short8v H, L;
        #pragma unroll
        for (int j = 0; j < 8; ++j) {
            float v = W2[(size_t)(k0 + j) * NH2 + col];
            unsigned short hh = f2bf(v);
            H[j] = (short)hh;
            L[j] = (short)f2bf(v - bf2f(hh));
        }
        ((short8v*)w2h)[i2] = H;
        ((short8v*)w2l)[i2] = L;
    }
}

__launch_bounds__(256, 3)
__global__ void fused_readout(const float* __restrict__ h, const float* __restrict__ x,
                              const int* __restrict__ batch,
                              const unsigned short* __restrict__ w1h,
                              const unsigned short* __restrict__ w2h,
                              const float* __restrict__ b1, const float* __restrict__ b2,
                              const float* __restrict__ Wout, const float* __restrict__ zbuf,
                              float* __restrict__ gf1d, int N)
{
    // 49152 B LDS, time-multiplexed (R8/R14 layout):
    //   [GEMM1] A fp32 ring: 3 bufs x [64 rows][64 fp32] = 49152 B
    //           (row stride 256 B; 16B-granule XOR swizzle c16 ^= row&15 applied
    //            on the GLOBAL SOURCE; LDS dest linear for global_load_lds)
    //   [GEMM2] F1h [64][256] bf16 = 32768 B (overlaps ring bufs 0-1)
    //   [pool ] s2p[2][64] f32 at 0, srow[64] f32 at byte 512
    __shared__ __align__(16) char lds[49152];
    unsigned short* F1h = (unsigned short*)lds;
    float* s2p  = (float*)lds;          // 128 floats
    float* srow = (float*)(lds + 512);  // 64 floats

    const int t    = threadIdx.x;
    const int lane = t & 63;
    const int w    = t >> 6;
    const int n0   = blockIdx.x * BM;
    const int l31  = lane & 31;
    const int hs   = lane >> 5;         // k-half select

    const short8v* W1H = (const short8v*)w1h;

    f32x16 acc00, acc01, acc10, acc11;
    #pragma unroll
    for (int r = 0; r < 16; ++r) { acc00[r] = 0.f; acc01[r] = 0.f; acc10[r] = 0.f; acc11[r] = 0.f; }

    // ---- helpers ----
    // issue 4 global_load_lds covering this wave's 16 rows of chunk CH into ring buffer BUF
    // dest: linear  BUF*16384 + brow*256 + lane*16
    // src : per-lane, pre-swizzled col16 = (lane&15) ^ (row&15); OOB -> zbuf
    #define AISSUE(CH, BUF) do {                                               \
        _Pragma("unroll")                                                      \
        for (int ii = 0; ii < 4; ++ii) {                                       \
            int brow = w*16 + ii*4;                                            \
            int row  = brow + (lane >> 4);                                     \
            int node = n0 + row;                                               \
            int colf = (CH)*64 + (((lane & 15) ^ (row & 15)) << 2);            \
            const float* src;                                                  \
            if (node >= N || colf >= DIN) src = zbuf + (lane & 15)*4;          \
            else if (colf < HID)          src = h + (size_t)node*HID + colf;   \
            else                          src = x + (size_t)node*EMB + (colf - HID); \
            __builtin_amdgcn_global_load_lds(                                  \
                (const __attribute__((address_space(1))) unsigned*)src,        \
                (__attribute__((address_space(3))) unsigned*)(lds + (BUF)*16384 + brow*256 + lane*16), \
                16, 0, 0);                                                     \
        } } while (0)

    // A fragment: row ROW, logical col16 pair {S*4+hs*2, +1} of ring buffer (byte base HB)
    #define AFRAG(HB, S, ROW)                                                  \
        cvt8(*(const float4*)(lds + (HB) + (ROW)*256 + ((((S)*4 + hs*2)     ^ ((ROW) & 15)) << 4)), \
             *(const float4*)(lds + (HB) + (ROW)*256 + ((((S)*4 + hs*2 + 1) ^ ((ROW) & 15)) << 4)))

    // load one k-step's 2 B hi-fragments into named regs
    #define BLOAD2(KS, H0, H1) do {                                            \
        size_t nb_ = ((size_t)((KS)*8 + w*2))*64 + lane;                       \
        H0 = W1H[nb_]; H1 = W1H[nb_ + 64]; } while (0)

    // ---- prologue: A chunks 0,1 in flight; B pipe filled to depth 3 ----
    AISSUE(0, 0);
    AISSUE(1, 1);
    short8v b0h0, b0h1, b1h0, b1h1, b2h0, b2h1;
    BLOAD2(0, b0h0, b0h1);
    BLOAD2(1, b1h0, b1h1);
    BLOAD2(2, b2h0, b2h1);

    // ================= GEMM1: 7 chunks x 4 k-steps, counted-vmcnt, B depth 3 =================
    #pragma unroll
    for (int c = 0; c < NCH; ++c) {
        // Loads newer than A(c) at this point (issue order: A0:4, A1:4, Bpro:6,
        // then per chunk: A(c+2):4 + B:8):
        //   c=0: 10   c=1: 18   c=2..5: 20   c=6: 16.
        // Counted waits with margin >=4 — never 0, never exact.
        if (c == 0) { asm volatile("s_waitcnt vmcnt(6)"  ::: "memory"); }
        else        { asm volatile("s_waitcnt vmcnt(12)" ::: "memory"); }
        __builtin_amdgcn_s_barrier();   // all waves' A(c) complete; ring (c+2)%3 free
        if (c + 2 < NCH) AISSUE(c + 2, (c + 2) % 3);

        const int hb = (c % 3) * 16384;
        #pragma unroll
        for (int s = 0; s < 4; ++s) {
            const int ks = c * 4 + s;
            // prefetch B(ks+3) (depth 3; dummy ks=0 at tail)
            short8v nh0, nh1;
            BLOAD2((ks + 3 < NKS1) ? ks + 3 : 0, nh0, nh1);
            // A fragments (LDS ring) + convert
            short8v ah0 = AFRAG(hb, s, l31);
            short8v ah1 = AFRAG(hb, s, 32 + l31);
            acc00 = __builtin_amdgcn_mfma_f32_32x32x16_bf16(ah0, b0h0, acc00, 0,0,0);
            acc01 = __builtin_amdgcn_mfma_f32_32x32x16_bf16(ah0, b0h1, acc01, 0,0,0);
            acc10 = __builtin_amdgcn_mfma_f32_32x32x16_bf16(ah1, b0h0, acc10, 0,0,0);
            acc11 = __builtin_amdgcn_mfma_f32_32x32x16_bf16(ah1, b0h1, acc11, 0,0,0);
            // rotate 3-deep B pipeline
            b0h0 = b1h0; b0h1 = b1h1;
            b1h0 = b2h0; b1h1 = b2h1;
            b2h0 = nh0;  b2h1 = nh1;
        }
    }
    #undef BLOAD2
    #undef AFRAG
    #undef AISSUE

    __syncthreads();   // all ring reads done; F1h may overwrite bufs 0-1

    // ---- GEMM2 B preload (issued here so L2 latency hides under EPI1+barrier) ----
    const int m2   = w >> 1;      // node-row half
    const int nt2  = w & 1;       // col half
    const short8v* W2H = (const short8v*)w2h;
    short8v g0 = W2H[(size_t)(0*2 + nt2)*64 + lane];
    short8v g1 = W2H[(size_t)(1*2 + nt2)*64 + lane];
    short8v g2 = W2H[(size_t)(2*2 + nt2)*64 + lane];
    short8v g3 = W2H[(size_t)(3*2 + nt2)*64 + lane];

    // ---- epilogue1: bias + relu + bf16 (hi only) -> F1h (XOR-swizzled) ----
    // C/D layout: col = lane&31, row = (r&3) + 8*(r>>2) + 4*(lane>>5)
    const float b1c0 = b1[w*64 + l31];
    const float b1c1 = b1[w*64 + 32 + l31];
#define EPI1(ACC, MI, NI) do {                                            \
        int gcol = w*64 + (NI)*32 + l31;                                  \
        float bb = (NI) ? b1c1 : b1c0;                                    \
        _Pragma("unroll")                                                 \
        for (int r = 0; r < 16; ++r) {                                    \
            int grow = (MI)*32 + (r & 3) + 8*(r >> 2) + 4*hs;             \
            float v = fmaxf(ACC[r] + bb, 0.f);                            \
            int phys = grow*256 + (((gcol >> 3) ^ (grow & 31)) << 3) + (gcol & 7); \
            F1h[phys] = f2bf(v);                                          \
        } } while (0)
    EPI1(acc00, 0, 0); EPI1(acc01, 0, 1); EPI1(acc10, 1, 0); EPI1(acc11, 1, 1);
#undef EPI1
    __syncthreads();

    // ================= GEMM2: feat2 = relu(feat1 @ W2 + b2) =================
    // A = bf16(feat1) hi-only; B = W2 hi-only (1 MFMA/step), pipe depth 4.
    f32x16 acc2;
    #pragma unroll
    for (int r = 0; r < 16; ++r) acc2[r] = 0.f;
    const int arow = m2*32 + l31;

    #pragma unroll
    for (int ks = 0; ks < NKS2; ++ks) {
        // prefetch B(ks+4) (depth 4; dummy index 0 at tail)
        short8v gn = W2H[(size_t)(((ks + 4 < NKS2) ? ks + 4 : 0)*2 + nt2)*64 + lane];
        int blk  = (ks*2 + hs) ^ (arow & 31);
        short8v ah2 = *(const short8v*)&F1h[arow*256 + blk*8];
        acc2 = __builtin_amdgcn_mfma_f32_32x32x16_bf16(ah2, g0, acc2, 0,0,0);
        g0 = g1; g1 = g2; g2 = g3; g3 = gn;
    }
    __syncthreads();   // all F1 reads done; s2p/srow may now overwrite LDS

    // ---- epilogue2: s_n = relu(feat2 + b2) . Wout, 32-col shfl reduce ----
    {
        const int   col2 = nt2*32 + l31;
        const float b2c  = b2[col2];
        const float woc  = Wout[col2];
        #pragma unroll
        for (int r = 0; r < 16; ++r) {
            float v = fmaxf(acc2[r] + b2c, 0.f) * woc;
            v += __shfl_xor(v, 1);
            v += __shfl_xor(v, 2);
            v += __shfl_xor(v, 4);
            v += __shfl_xor(v, 8);
            v += __shfl_xor(v, 16);
            if (l31 == 0) {
                int grow = m2*32 + (r & 3) + 8*(r >> 2) + 4*hs;
                s2p[nt2*64 + grow] = v;   // [colhalf][row]
            }
        }
    }
    __syncthreads();
    if (t < 64) srow[t] = s2p[t] + s2p[64 + t];
    __syncthreads();

    // ---- wave-parallel segmented sum over sorted batch (wave 0 only) ----
    // Prefix-sum over 64 lanes + ballot head-mask; one atomicAdd per run head.
    // ALL shuffles executed by all 64 lanes (no divergent-source UB, R19 fix);
    // only the atomicAdd is predicated.
    if (t < 64) {
        const int node = n0 + t;
        const int b = (node < N) ? batch[node] : -1;
        float v = (b >= 0) ? srow[t] : 0.f;

        // inclusive prefix sum P[t] = sum_{j<=t} v[j]
        float P = v;
        #pragma unroll
        for (int d = 1; d < 64; d <<= 1) {
            float u = __shfl_up(P, d);
            if (t >= d) P += u;
        }

        const int bprev = __shfl_up(b, 1);
        const bool newseg = (t == 0) || (b != bprev);
        const unsigned long long hm = __ballot(newseg);
        // next head strictly after t
        unsigned long long hi = (t < 63) ? (hm >> (t + 1)) : 0ull;
        const int e = hi ? (t + 1 + (int)__builtin_ctzll(hi)) : 64;
        // ALL lanes execute the shuffle (e-1 in [0,63] for every lane)
        float Pe = __shfl(P, e - 1);
        if (newseg && b >= 0) {
            float sum = Pe - P + v;           // sum of srow over [t, e-1]
            atomicAdd(&gf1d[b], sum);
        }
    }
}

__global__ void final_sigmoid(const float* __restrict__ gf1d, const float* __restrict__ bout,
                              float* __restrict__ out, int G)
{
    int g = blockIdx.x * 256 + threadIdx.x;
    if (g < G) out[g] = 1.f / (1.f + expf(-(gf1d[g] + bout[0])));
}

extern "C" void kernel_launch(void* const* d_in, const int* in_sizes, int n_in,
                              void* d_out, int out_size, void* d_ws, size_t ws_size,
                              hipStream_t stream)
{
    const float* h    = (const float*)d_in[0];
    const float* x    = (const float*)d_in[1];
    const int*   batch= (const int*)d_in[2];
    const float* W1   = (const float*)d_in[3];
    const float* b1   = (const float*)d_in[4];
    const float* W2   = (const float*)d_in[5];
    const float* b2   = (const float*)d_in[6];
    const float* Wout = (const float*)d_in[7];
    const float* bout = (const float*)d_in[8];
    float* out = (float*)d_out;

    const int N = in_sizes[2];
    const int G = out_size;

    // workspace layout (~305 KB total)
    char* ws = (char*)d_ws;
    float* gf1d = (float*)ws;                                  //   8,192 B
    float* zbuf = (float*)(ws + 8192);                         //   1,024 B (zeros)
    unsigned short* w1h = (unsigned short*)(ws + 9216);        // 229,376 B
    unsigned short* w2h = w1h + (size_t)W1P_SH8 * 8;           //  32,768 B
    unsigned short* w2l = w2h + (size_t)W2P_SH8 * 8;           //  32,768 B (packed, unused)

    hipMemsetAsync(gf1d, 0, 9216, stream);   // gf accumulators + zero buffer
    pack_weights<<<(W1P_SH8 + W2P_SH8 + 255) / 256, 256, 0, stream>>>(W1, W2, w1h, w2h, w2l);
    fused_readout<<<(N + BM - 1) / BM, 256, 0, stream>>>(h, x, batch, w1h, w2h,
                                                         b1, b2, Wout, zbuf, gf1d, N);
    final_sigmoid<<<(G + 255) / 256, 256, 0, stream>>>(gf1d, bout, out, G);
}

// Round 21
// 121.950 us; speedup vs baseline: 1.7323x; 1.0185x over previous
//
#include <hip/hip_runtime.h>
#include <hip/hip_bf16.h>
#include <math.h>

// Fused GNN readout via bf16 MFMA (v_mfma_f32_32x32x16_bf16):
//   feat1 = relu(concat(h,x) @ W1 + b1)   [N,256]  GEMM1: K=400(pad 448), A=bf16 hi, B=W1 hi ONLY
//   feat2 = relu(feat1 @ W2 + b2)         [N,64]   GEMM2: K=256, A=bf16 hi, B=W2 hi ONLY
//   s_n   = feat2 . Wout ; out = sigmoid(segment_sum(s_n) + bout)
// R21 = R20 (124.2us) + two cheap deltas:
//   - gf/zbuf zeroing folded into pack_weights (one fewer serial dispatch;
//     same-stream ordering preserves zero-before-atomics; runs every call).
//   - GEMM2 A-read prefetched 1 step ahead (B preloaded depth-4 already;
//     the 16-step ds_read->MFMA chain was serial).

typedef __attribute__((ext_vector_type(8)))  short short8v;
typedef __attribute__((ext_vector_type(16))) float f32x16;

#define G_NUM 2048
#define HID 200
#define EMB 200
#define DIN 400
#define NH1 256
#define NH2 64
#define BM  64
#define NKS1 28        // bf16 K-steps (of 16) for GEMM1, K padded 400->448
#define NCH  7         // 7 chunks of 64 fp32 cols
#define NKS2 16        // K-steps for GEMM2 (K=256)

#define W1P_SH8 (NKS1*8*64)   // 14336 fragments (16B each), hi plane only
#define W2P_SH8 (NKS2*2*64)   // 2048

__device__ __forceinline__ unsigned short f2bf(float f) {
    union { float f; unsigned u; } v; v.f = f;
    unsigned r = v.u + 0x7fffu + ((v.u >> 16) & 1u);   // RNE
    return (unsigned short)(r >> 16);
}
__device__ __forceinline__ float bf2f(unsigned short b) {
    union { unsigned u; float f; } v; v.u = ((unsigned)b) << 16;
    return v.f;
}
// 8 fp32 -> 8 bf16 (RNE) via packed converts
__device__ __forceinline__ short8v cvt8(float4 a, float4 b) {
    union { __hip_bfloat162 q[4]; short8v s8; } u;
    u.q[0] = __float22bfloat162_rn(make_float2(a.x, a.y));
    u.q[1] = __float22bfloat162_rn(make_float2(a.z, a.w));
    u.q[2] = __float22bfloat162_rn(make_float2(b.x, b.y));
    u.q[3] = __float22bfloat162_rn(make_float2(b.z, b.w));
    return u.s8;
}

// Pre-pack W1 (hi only) / W2 (hi) into MFMA-fragment order; also zeroes the
// gf accumulators + zbuf (replaces the separate hipMemsetAsync dispatch —
// same-stream ordering guarantees zeros land before fused_readout's atomics).
// Fragment (ks, ntile, lane) holds 8 bf16: B[k0+j][col], k0=ks*16+(lane>>5)*8,
// col=ntile*32+(lane&31). Contiguous-8 k in BOTH A and B => any consistent
// hw k-permutation cancels in the dot product.
__global__ void pack_weights(const float* __restrict__ W1, const float* __restrict__ W2,
                             unsigned short* __restrict__ w1h,
                             unsigned short* __restrict__ w2h,
                             float* __restrict__ gfz)   // gf[2048] + zbuf[256]
{
    int idx = blockIdx.x * 256 + threadIdx.x;
    if (idx < G_NUM + 256) gfz[idx] = 0.f;
    if (idx < W1P_SH8) {
        int l  = idx & 63;
        int nt = (idx >> 6) & 7;
        int ks = idx >> 9;
        int col = nt * 32 + (l & 31);
        int k0  = ks * 16 + (l >> 5) * 8;
        short8v H;
        #pragma unroll
        for (int j = 0; j < 8; ++j) {
            int k = k0 + j;
            H[j] = (short)f2bf((k < DIN) ? W1[(size_t)k * NH1 + col] : 0.f);
        }
        ((short8v*)w1h)[idx] = H;
    } else if (idx < W1P_SH8 + W2P_SH8) {
        int i2 = idx - W1P_SH8;
        int l  = i2 & 63;
        int nt = (i2 >> 6) & 1;
        int ks = i2 >> 7;
        int col = nt * 32 + (l & 31);
        int k0  = ks * 16 + (l >> 5) * 8;
        short8v H;
        #pragma unroll
        for (int j = 0; j < 8; ++j)
            H[j] = (short)f2bf(W2[(size_t)(k0 + j) * NH2 + col]);
        ((short8v*)w2h)[i2] = H;
    }
}

__launch_bounds__(256, 3)
__global__ void fused_readout(const float* __restrict__ h, const float* __restrict__ x,
                              const int* __restrict__ batch,
                              const unsigned short* __restrict__ w1h,
                              const unsigned short* __restrict__ w2h,
                              const float* __restrict__ b1, const float* __restrict__ b2,
                              const float* __restrict__ Wout, const float* __restrict__ zbuf,
                              float* __restrict__ gf1d, int N)
{
    // 49152 B LDS, time-multiplexed (R8/R14 layout):
    //   [GEMM1] A fp32 ring: 3 bufs x [64 rows][64 fp32] = 49152 B
    //           (row stride 256 B; 16B-granule XOR swizzle c16 ^= row&15 applied
    //            on the GLOBAL SOURCE; LDS dest linear for global_load_lds)
    //   [GEMM2] F1h [64][256] bf16 = 32768 B (overlaps ring bufs 0-1)
    //   [pool ] s2p[2][64] f32 at 0, srow[64] f32 at byte 512
    __shared__ __align__(16) char lds[49152];
    unsigned short* F1h = (unsigned short*)lds;
    float* s2p  = (float*)lds;          // 128 floats
    float* srow = (float*)(lds + 512);  // 64 floats

    const int t    = threadIdx.x;
    const int lane = t & 63;
    const int w    = t >> 6;
    const int n0   = blockIdx.x * BM;
    const int l31  = lane & 31;
    const int hs   = lane >> 5;         // k-half select

    const short8v* W1H = (const short8v*)w1h;

    f32x16 acc00, acc01, acc10, acc11;
    #pragma unroll
    for (int r = 0; r < 16; ++r) { acc00[r] = 0.f; acc01[r] = 0.f; acc10[r] = 0.f; acc11[r] = 0.f; }

    // ---- helpers ----
    // issue 4 global_load_lds covering this wave's 16 rows of chunk CH into ring buffer BUF
    // dest: linear  BUF*16384 + brow*256 + lane*16
    // src : per-lane, pre-swizzled col16 = (lane&15) ^ (row&15); OOB -> zbuf
    #define AISSUE(CH, BUF) do {                                               \
        _Pragma("unroll")                                                      \
        for (int ii = 0; ii < 4; ++ii) {                                       \
            int brow = w*16 + ii*4;                                            \
            int row  = brow + (lane >> 4);                                     \
            int node = n0 + row;                                               \
            int colf = (CH)*64 + (((lane & 15) ^ (row & 15)) << 2);            \
            const float* src;                                                  \
            if (node >= N || colf >= DIN) src = zbuf + (lane & 15)*4;          \
            else if (colf < HID)          src = h + (size_t)node*HID + colf;   \
            else                          src = x + (size_t)node*EMB + (colf - HID); \
            __builtin_amdgcn_global_load_lds(                                  \
                (const __attribute__((address_space(1))) unsigned*)src,        \
                (__attribute__((address_space(3))) unsigned*)(lds + (BUF)*16384 + brow*256 + lane*16), \
                16, 0, 0);                                                     \
        } } while (0)

    // A fragment: row ROW, logical col16 pair {S*4+hs*2, +1} of ring buffer (byte base HB)
    #define AFRAG(HB, S, ROW)                                                  \
        cvt8(*(const float4*)(lds + (HB) + (ROW)*256 + ((((S)*4 + hs*2)     ^ ((ROW) & 15)) << 4)), \
             *(const float4*)(lds + (HB) + (ROW)*256 + ((((S)*4 + hs*2 + 1) ^ ((ROW) & 15)) << 4)))

    // load one k-step's 2 B hi-fragments into named regs
    #define BLOAD2(KS, H0, H1) do {                                            \
        size_t nb_ = ((size_t)((KS)*8 + w*2))*64 + lane;                       \
        H0 = W1H[nb_]; H1 = W1H[nb_ + 64]; } while (0)

    // ---- prologue: A chunks 0,1 in flight; B pipe filled to depth 3 ----
    AISSUE(0, 0);
    AISSUE(1, 1);
    short8v b0h0, b0h1, b1h0, b1h1, b2h0, b2h1;
    BLOAD2(0, b0h0, b0h1);
    BLOAD2(1, b1h0, b1h1);
    BLOAD2(2, b2h0, b2h1);

    // ================= GEMM1: 7 chunks x 4 k-steps, counted-vmcnt, B depth 3 =================
    #pragma unroll
    for (int c = 0; c < NCH; ++c) {
        // Loads newer than A(c) at this point (issue order: A0:4, A1:4, Bpro:6,
        // then per chunk: A(c+2):4 + B:8):
        //   c=0: 10   c=1: 18   c=2..5: 20   c=6: 16.
        // Counted waits with margin >=4 — never 0, never exact.
        if (c == 0) { asm volatile("s_waitcnt vmcnt(6)"  ::: "memory"); }
        else        { asm volatile("s_waitcnt vmcnt(12)" ::: "memory"); }
        __builtin_amdgcn_s_barrier();   // all waves' A(c) complete; ring (c+2)%3 free
        if (c + 2 < NCH) AISSUE(c + 2, (c + 2) % 3);

        const int hb = (c % 3) * 16384;
        #pragma unroll
        for (int s = 0; s < 4; ++s) {
            const int ks = c * 4 + s;
            // prefetch B(ks+3) (depth 3; dummy ks=0 at tail)
            short8v nh0, nh1;
            BLOAD2((ks + 3 < NKS1) ? ks + 3 : 0, nh0, nh1);
            // A fragments (LDS ring) + convert
            short8v ah0 = AFRAG(hb, s, l31);
            short8v ah1 = AFRAG(hb, s, 32 + l31);
            acc00 = __builtin_amdgcn_mfma_f32_32x32x16_bf16(ah0, b0h0, acc00, 0,0,0);
            acc01 = __builtin_amdgcn_mfma_f32_32x32x16_bf16(ah0, b0h1, acc01, 0,0,0);
            acc10 = __builtin_amdgcn_mfma_f32_32x32x16_bf16(ah1, b0h0, acc10, 0,0,0);
            acc11 = __builtin_amdgcn_mfma_f32_32x32x16_bf16(ah1, b0h1, acc11, 0,0,0);
            // rotate 3-deep B pipeline
            b0h0 = b1h0; b0h1 = b1h1;
            b1h0 = b2h0; b1h1 = b2h1;
            b2h0 = nh0;  b2h1 = nh1;
        }
    }
    #undef BLOAD2
    #undef AFRAG
    #undef AISSUE

    __syncthreads();   // all ring reads done; F1h may overwrite bufs 0-1

    // ---- GEMM2 B preload (issued here so L2 latency hides under EPI1+barrier) ----
    const int m2   = w >> 1;      // node-row half
    const int nt2  = w & 1;       // col half
    const short8v* W2H = (const short8v*)w2h;
    short8v g0 = W2H[(size_t)(0*2 + nt2)*64 + lane];
    short8v g1 = W2H[(size_t)(1*2 + nt2)*64 + lane];
    short8v g2 = W2H[(size_t)(2*2 + nt2)*64 + lane];
    short8v g3 = W2H[(size_t)(3*2 + nt2)*64 + lane];

    // ---- epilogue1: bias + relu + bf16 (hi only) -> F1h (XOR-swizzled) ----
    // C/D layout: col = lane&31, row = (r&3) + 8*(r>>2) + 4*(lane>>5)
    const float b1c0 = b1[w*64 + l31];
    const float b1c1 = b1[w*64 + 32 + l31];
#define EPI1(ACC, MI, NI) do {                                            \
        int gcol = w*64 + (NI)*32 + l31;                                  \
        float bb = (NI) ? b1c1 : b1c0;                                    \
        _Pragma("unroll")                                                 \
        for (int r = 0; r < 16; ++r) {                                    \
            int grow = (MI)*32 + (r & 3) + 8*(r >> 2) + 4*hs;             \
            float v = fmaxf(ACC[r] + bb, 0.f);                            \
            int phys = grow*256 + (((gcol >> 3) ^ (grow & 31)) << 3) + (gcol & 7); \
            F1h[phys] = f2bf(v);                                          \
        } } while (0)
    EPI1(acc00, 0, 0); EPI1(acc01, 0, 1); EPI1(acc10, 1, 0); EPI1(acc11, 1, 1);
#undef EPI1
    __syncthreads();

    // ================= GEMM2: feat2 = relu(feat1 @ W2 + b2) =================
    // A = bf16(feat1) hi-only (prefetched 1 step ahead); B = W2 hi-only, depth 4.
    f32x16 acc2;
    #pragma unroll
    for (int r = 0; r < 16; ++r) acc2[r] = 0.f;
    const int arow = m2*32 + l31;

    short8v aNext;
    {
        int blk0 = (0*2 + hs) ^ (arow & 31);
        aNext = *(const short8v*)&F1h[arow*256 + blk0*8];
    }
    #pragma unroll
    for (int ks = 0; ks < NKS2; ++ks) {
        // prefetch B(ks+4) (depth 4; dummy index 0 at tail)
        short8v gn = W2H[(size_t)(((ks + 4 < NKS2) ? ks + 4 : 0)*2 + nt2)*64 + lane];
        short8v aCur = aNext;
        if (ks + 1 < NKS2) {
            int blk = ((ks + 1)*2 + hs) ^ (arow & 31);
            aNext = *(const short8v*)&F1h[arow*256 + blk*8];
        }
        acc2 = __builtin_amdgcn_mfma_f32_32x32x16_bf16(aCur, g0, acc2, 0,0,0);
        g0 = g1; g1 = g2; g2 = g3; g3 = gn;
    }
    __syncthreads();   // all F1 reads done; s2p/srow may now overwrite LDS

    // ---- epilogue2: s_n = relu(feat2 + b2) . Wout, 32-col shfl reduce ----
    {
        const int   col2 = nt2*32 + l31;
        const float b2c  = b2[col2];
        const float woc  = Wout[col2];
        #pragma unroll
        for (int r = 0; r < 16; ++r) {
            float v = fmaxf(acc2[r] + b2c, 0.f) * woc;
            v += __shfl_xor(v, 1);
            v += __shfl_xor(v, 2);
            v += __shfl_xor(v, 4);
            v += __shfl_xor(v, 8);
            v += __shfl_xor(v, 16);
            if (l31 == 0) {
                int grow = m2*32 + (r & 3) + 8*(r >> 2) + 4*hs;
                s2p[nt2*64 + grow] = v;   // [colhalf][row]
            }
        }
    }
    __syncthreads();
    if (t < 64) srow[t] = s2p[t] + s2p[64 + t];
    __syncthreads();

    // ---- wave-parallel segmented sum over sorted batch (wave 0 only) ----
    // Prefix-sum over 64 lanes + ballot head-mask; one atomicAdd per run head.
    // ALL shuffles executed by all 64 lanes (no divergent-source UB);
    // only the atomicAdd is predicated.
    if (t < 64) {
        const int node = n0 + t;
        const int b = (node < N) ? batch[node] : -1;
        float v = (b >= 0) ? srow[t] : 0.f;

        // inclusive prefix sum P[t] = sum_{j<=t} v[j]
        float P = v;
        #pragma unroll
        for (int d = 1; d < 64; d <<= 1) {
            float u = __shfl_up(P, d);
            if (t >= d) P += u;
        }

        const int bprev = __shfl_up(b, 1);
        const bool newseg = (t == 0) || (b != bprev);
        const unsigned long long hm = __ballot(newseg);
        // next head strictly after t
        unsigned long long hi = (t < 63) ? (hm >> (t + 1)) : 0ull;
        const int e = hi ? (t + 1 + (int)__builtin_ctzll(hi)) : 64;
        // ALL lanes execute the shuffle (e-1 in [0,63] for every lane)
        float Pe = __shfl(P, e - 1);
        if (newseg && b >= 0) {
            float sum = Pe - P + v;           // sum of srow over [t, e-1]
            atomicAdd(&gf1d[b], sum);
        }
    }
}

__global__ void final_sigmoid(const float* __restrict__ gf1d, const float* __restrict__ bout,
                              float* __restrict__ out, int G)
{
    int g = blockIdx.x * 256 + threadIdx.x;
    if (g < G) out[g] = 1.f / (1.f + expf(-(gf1d[g] + bout[0])));
}

extern "C" void kernel_launch(void* const* d_in, const int* in_sizes, int n_in,
                              void* d_out, int out_size, void* d_ws, size_t ws_size,
                              hipStream_t stream)
{
    const float* h    = (const float*)d_in[0];
    const float* x    = (const float*)d_in[1];
    const int*   batch= (const int*)d_in[2];
    const float* W1   = (const float*)d_in[3];
    const float* b1   = (const float*)d_in[4];
    const float* W2   = (const float*)d_in[5];
    const float* b2   = (const float*)d_in[6];
    const float* Wout = (const float*)d_in[7];
    const float* bout = (const float*)d_in[8];
    float* out = (float*)d_out;

    const int N = in_sizes[2];
    const int G = out_size;

    // workspace layout (~272 KB total)
    char* ws = (char*)d_ws;
    float* gf1d = (float*)ws;                                  //   8,192 B (gf)
    float* zbuf = (float*)(ws + 8192);                         //   1,024 B (zeros)
    unsigned short* w1h = (unsigned short*)(ws + 9216);        // 229,376 B
    unsigned short* w2h = w1h + (size_t)W1P_SH8 * 8;           //  32,768 B

    // pack_weights also zeroes gf+zbuf (same stream => ordered before atomics)
    pack_weights<<<(W1P_SH8 + W2P_SH8 + 255) / 256, 256, 0, stream>>>(W1, W2, w1h, w2h, gf1d);
    fused_readout<<<(N + BM - 1) / BM, 256, 0, stream>>>(h, x, batch, w1h, w2h,
                                                         b1, b2, Wout, zbuf, gf1d, N);
    final_sigmoid<<<(G + 255) / 256, 256, 0, stream>>>(gf1d, bout, out, G);
}